// Round 9
// baseline (311.469 us; speedup 1.0000x reference)
//
#include <hip/hip_runtime.h>
#include <hip/hip_bf16.h>

#define B_ 4
#define N_ 8192
#define M_ 2048
#define K_ 8

typedef __bf16 bf16x8 __attribute__((ext_vector_type(8)));
typedef __bf16 bf16x4 __attribute__((ext_vector_type(4)));
typedef float  floatx4 __attribute__((ext_vector_type(4)));
typedef unsigned long long u64k;

#define AS1G __attribute__((address_space(1)))
#define AS3L __attribute__((address_space(3)))

// ---------------------------------------------------------------------------
// PRE_KNN (fused independent work) -- identical to R8 (split-4 was a win):
//   blocks [0,2048)      : KNN split-4, 64 pts & 512 candidates per block
//   blocks [2048,4096)   : feature2 fp32 -> f2t bf16 transpose
//   blocks [4096,12288)  : feature1 fp32 -> f1t bf16 transpose
//   blocks [12288,13136) : weight casts (w1_0 padded 259->288)
// smem = 24576 B -> 6 blocks/CU for the VALU-bound scan.
// ---------------------------------------------------------------------------
__device__ __forceinline__ void ce(u64k& a, u64k& b) {
  u64k lo = a < b ? a : b;
  u64k hi = a < b ? b : a;
  a = lo; b = hi;
}

// low-8 of merge(a asc, c asc), result sorted ascending (bitonic clean)
__device__ __forceinline__ void merge8(u64k (&a)[8], const u64k (&c)[8]) {
  #pragma unroll
  for (int k = 0; k < 8; k++) { u64k x = c[7 - k]; a[k] = a[k] < x ? a[k] : x; }
  ce(a[0], a[4]); ce(a[1], a[5]); ce(a[2], a[6]); ce(a[3], a[7]);
  ce(a[0], a[2]); ce(a[1], a[3]); ce(a[4], a[6]); ce(a[5], a[7]);
  ce(a[0], a[1]); ce(a[2], a[3]); ce(a[4], a[5]); ce(a[6], a[7]);
}

__global__ __launch_bounds__(256) void pre_knn(
    const float* __restrict__ w10, const float* __restrict__ w11,
    const float* __restrict__ w12, const float* __restrict__ w20,
    const float* __restrict__ feature1, const float* __restrict__ feature2,
    const float* __restrict__ pos1, const float* __restrict__ pos2,
    __bf16* __restrict__ w0p, __bf16* __restrict__ w11b,
    __bf16* __restrict__ w12b, __bf16* __restrict__ w20b,
    __bf16* __restrict__ f2t, __bf16* __restrict__ f1t,
    u64k* __restrict__ part)
{
  __shared__ __align__(16) char smem[24576];
  const int bid = blockIdx.x;
  const int tid = threadIdx.x;

  if (bid < 2048) {
    // ---------------- KNN (split-4) ----------------
    floatx4* P = (floatx4*)smem;                     // 512 x 16B = 8 KB
    u64k (*md)[32] = (u64k(*)[32])(smem + 8192);     // 16 KB (unpadded)
    const int b = (bid >> 7) & 3;
    const int quarter = bid >> 9;                    // 0..3
    const int n0 = (bid & 127) * 64;
    const int cbase = quarter * 512;

    const float* p2 = pos2 + b * 3 * M_;
    for (int i = tid; i < 512; i += 256) {
      const int c = cbase + i;
      float x = p2[c], y = p2[M_ + c], z = p2[2 * M_ + c];
      floatx4 q;
      q[0] = x; q[1] = y; q[2] = z;
      q[3] = __fadd_rn(__fadd_rn(__fmul_rn(x, x), __fmul_rn(y, y)), __fmul_rn(z, z));
      P[i] = q;
    }
    __syncthreads();

    const int p = tid >> 2, t = tid & 3;
    const int n = n0 + p;
    const float* p1 = pos1 + b * 3 * N_;
    const float x1 = p1[n], y1 = p1[N_ + n], z1 = p1[2 * N_ + n];
    const float r1 = __fadd_rn(__fadd_rn(__fmul_rn(x1, x1), __fmul_rn(y1, y1)),
                               __fmul_rn(z1, z1));

    u64k bd[8];
    #pragma unroll
    for (int r = 0; r < 8; r++) bd[r] = ~0ULL;   // sentinel > any real key

    for (int bb = 0; bb < 16; ++bb) {
      // interleaved per-thread stream (index-ascending): local c = 4*(8bb+i)+t
      floatx4 q[8];
      #pragma unroll
      for (int i = 0; i < 8; i++) q[i] = P[4 * (8 * bb + i) + t];

      u64k s[8];
      #pragma unroll
      for (int i = 0; i < 8; i++) {
        float dot = __fadd_rn(__fadd_rn(__fmul_rn(x1, q[i][0]), __fmul_rn(y1, q[i][1])),
                              __fmul_rn(z1, q[i][2]));
        float d = __fsub_rn(__fadd_rn(r1, q[i][3]), __fmul_rn(2.0f, dot));
        unsigned du = __float_as_uint(d);
        unsigned k32 = du ^ ((unsigned)((int)du >> 31) | 0x80000000u);  // monotone
        s[i] = ((u64k)k32 << 11) | (unsigned)(cbase + 4 * (8 * bb + i) + t);
      }

      // Batcher odd-even mergesort, 8 elements, 19 comparators
      ce(s[0], s[1]); ce(s[2], s[3]); ce(s[4], s[5]); ce(s[6], s[7]);
      ce(s[0], s[2]); ce(s[1], s[3]); ce(s[4], s[6]); ce(s[5], s[7]);
      ce(s[1], s[2]); ce(s[5], s[6]);
      ce(s[0], s[4]); ce(s[1], s[5]); ce(s[2], s[6]); ce(s[3], s[7]);
      ce(s[2], s[4]); ce(s[3], s[5]);
      ce(s[1], s[2]); ce(s[3], s[4]); ce(s[5], s[6]);

      if (s[0] < bd[7]) merge8(bd, s);
    }

    // column XOR-swizzle (t-field) replaces +1 row pad for bank spread
    {
      const int swp = (p & 3) << 3;
      #pragma unroll
      for (int r = 0; r < 8; r++) md[p][(t * 8 + r) ^ swp] = bd[r];
    }
    __syncthreads();

    // 4-way lexicographic merge of the sorted lists == lax.top_k order
    if (tid < 64) {
      const int sw = tid & 3;
      const int b0 = (0 ^ sw) << 3, b1 = (1 ^ sw) << 3;
      const int b2 = (2 ^ sw) << 3, b3 = (3 ^ sw) << 3;
      int h0 = 0, h1 = 0, h2 = 0, h3 = 0;
      u64k* o = part + ((size_t)((b * 4 + quarter) * N_ + n0 + tid)) * 8;
      #pragma unroll
      for (int r = 0; r < 8; r++) {
        u64k k0 = md[tid][b0 + h0], k1 = md[tid][b1 + h1];
        u64k k2 = md[tid][b2 + h2], k3 = md[tid][b3 + h3];
        u64k m01 = k0 < k1 ? k0 : k1;
        u64k m23 = k2 < k3 ? k2 : k3;
        u64k m = m01 < m23 ? m01 : m23;
        h0 += (k0 == m); h1 += (k1 == m); h2 += (k2 == m); h3 += (k3 == m);
        o[r] = m;
      }
    }
  } else if (bid < 4096) {
    // ---------------- feature2 transpose+cast (L = M_) ----------------
    float (*tile)[33] = (float(*)[33])smem;
    const int tb = bid - 2048;
    const int C = 256, L = M_;
    const int b = tb >> 9;
    const int c0 = ((tb >> 6) & 7) * 32, l0 = (tb & 63) * 32;
    const int tx = tid & 31, ty = tid >> 5;
    const float* src = feature2 + (size_t)b * C * L;
    #pragma unroll
    for (int i = 0; i < 4; i++)
      tile[ty + 8 * i][tx] = src[(size_t)(c0 + ty + 8 * i) * L + l0 + tx];
    __syncthreads();
    __bf16* dst = f2t + (size_t)b * L * C;
    #pragma unroll
    for (int i = 0; i < 4; i++)
      dst[(size_t)(l0 + ty + 8 * i) * C + c0 + tx] = (__bf16)tile[tx][ty + 8 * i];
  } else if (bid < 12288) {
    // ---------------- feature1 transpose+cast (L = N_) ----------------
    float (*tile)[33] = (float(*)[33])smem;
    const int tb = bid - 4096;
    const int C = 256, L = N_;
    const int b = tb >> 11;
    const int c0 = ((tb >> 8) & 7) * 32, l0 = (tb & 255) * 32;
    const int tx = tid & 31, ty = tid >> 5;
    const float* src = feature1 + (size_t)b * C * L;
    #pragma unroll
    for (int i = 0; i < 4; i++)
      tile[ty + 8 * i][tx] = src[(size_t)(c0 + ty + 8 * i) * L + l0 + tx];
    __syncthreads();
    __bf16* dst = f1t + (size_t)b * L * C;
    #pragma unroll
    for (int i = 0; i < 4; i++)
      dst[(size_t)(l0 + ty + 8 * i) * C + c0 + tx] = (__bf16)tile[tx][ty + 8 * i];
  } else {
    // ---------------- weight casts ----------------
    int t = (bid - 12288) * 256 + tid;
    if (t < 36864) {
      int o = t / 288, c = t - o * 288;
      w0p[t] = (c < 259) ? (__bf16)w10[o * 259 + c] : (__bf16)0.0f;
    } else if (t < 53248) {
      int i = t - 36864; w11b[i] = (__bf16)w11[i];
    } else if (t < 86016) {
      int i = t - 53248; w12b[i] = (__bf16)w12[i];
    } else if (t < 217088) {
      int i = t - 86016; w20b[i] = (__bf16)w20[i];
    }
  }
}

// ---------------------------------------------------------------------------
// Merge the four candidate-quarter sorted-8 key lists -> final neighbor
// indices (identical to R8).
// ---------------------------------------------------------------------------
__global__ __launch_bounds__(256) void knn_merge(
    const u64k* __restrict__ part, int* __restrict__ idx_out)
{
  const int pt = blockIdx.x * 256 + threadIdx.x;     // 0..32767
  const int b = pt >> 13, n = pt & (N_ - 1);
  u64k a01[8], c1[8], a23[8], c3[8];
  {
    const u64k* l0 = part + ((size_t)((b * 4 + 0) * N_ + n)) * 8;
    const u64k* l1 = part + ((size_t)((b * 4 + 1) * N_ + n)) * 8;
    const u64k* l2 = part + ((size_t)((b * 4 + 2) * N_ + n)) * 8;
    const u64k* l3 = part + ((size_t)((b * 4 + 3) * N_ + n)) * 8;
    #pragma unroll
    for (int r = 0; r < 8; r++) {
      a01[r] = l0[r]; c1[r] = l1[r]; a23[r] = l2[r]; c3[r] = l3[r];
    }
  }
  merge8(a01, c1);
  merge8(a23, c3);
  merge8(a01, a23);
  int* o = idx_out + (size_t)pt * 8;
  #pragma unroll
  for (int r = 0; r < 8; r++) o[r] = (int)(a01[r] & 2047u);
}

// ---------------------------------------------------------------------------
// Swizzled-X MFMA k-loop (no epilogue) -- verified mlp1 component.
// ---------------------------------------------------------------------------
template <int KSTEPS>
__device__ __forceinline__ void mfma_kloop_swz(
    const __bf16* X, const __bf16* W, int wstride, int c0, int lane,
    floatx4 (&acc)[4][2])
{
  const int lrow = lane & 15, quad = lane >> 4;
  const floatx4 fz = {0.f, 0.f, 0.f, 0.f};
  #pragma unroll
  for (int pt = 0; pt < 4; pt++) { acc[pt][0] = fz; acc[pt][1] = fz; }

  bf16x8 wf0 = *(const bf16x8*)(W + (size_t)(c0 + lrow) * wstride + quad * 8);
  bf16x8 wf1 = *(const bf16x8*)(W + (size_t)(c0 + 16 + lrow) * wstride + quad * 8);
  bf16x8 xf[4];
  #pragma unroll
  for (int pt = 0; pt < 4; pt++) {
    const int row = pt * 16 + lrow;
    xf[pt] = *(const bf16x8*)((const char*)X + row * 256
                              + ((quad * 16) ^ ((row & 7) << 4)));
  }

  #pragma unroll
  for (int ks = 0; ks < KSTEPS; ks++) {
    bf16x8 wn0, wn1, xn[4];
    if (ks + 1 < KSTEPS) {
      const int kn = (ks + 1) * 32 + quad * 8;
      wn0 = *(const bf16x8*)(W + (size_t)(c0 + lrow) * wstride + kn);
      wn1 = *(const bf16x8*)(W + (size_t)(c0 + 16 + lrow) * wstride + kn);
      #pragma unroll
      for (int pt = 0; pt < 4; pt++) {
        const int row = pt * 16 + lrow;
        xn[pt] = *(const bf16x8*)((const char*)X + row * 256
                                  + (((ks + 1) * 64 + quad * 16) ^ ((row & 7) << 4)));
      }
    }
    #pragma unroll
    for (int pt = 0; pt < 4; pt++) {
      acc[pt][0] = __builtin_amdgcn_mfma_f32_16x16x32_bf16(wf0, xf[pt], acc[pt][0], 0, 0, 0);
      acc[pt][1] = __builtin_amdgcn_mfma_f32_16x16x32_bf16(wf1, xf[pt], acc[pt][1], 0, 0, 0);
    }
    if (ks + 1 < KSTEPS) {
      wf0 = wn0; wf1 = wn1;
      #pragma unroll
      for (int pt = 0; pt < 4; pt++) xf[pt] = xn[pt];
    }
  }
}

// ---------------------------------------------------------------------------
// MLP1 v7: v5 structure with Y0 given its OWN 16KB (no Xs alias) so the
// barrier between the L0 k-loop and its epilogue is DELETED -- kloop flows
// straight into the Y0 write (v2, the fastest measured config at 99.6us, had
// exactly this topology; v5's extra mid-block rendezvous is the suspected
// +5us). LDS = 48KB -> 3 blocks/CU (v2 evidence: 3 blocks beats 4 when a
// barrier is saved). Barriers 5 -> 4:
//   (1) post-DMA  (2) Y0 ready (also all-Xs-reads-done -> Y1 alias safe)
//   (3) Y1 ready (-> Mst alias safe)  (4) Mst complete.
// In-register shfl maxpool + full 512B/point coalesced stores kept from v5.
// ---------------------------------------------------------------------------
__global__ __launch_bounds__(256, 3) void mlp1_kernel(
    const float* __restrict__ pos1, const float* __restrict__ pos2,
    const int* __restrict__ idx, const __bf16* __restrict__ f2t,
    const __bf16* __restrict__ w0p, const float* __restrict__ s10, const float* __restrict__ b10,
    const __bf16* __restrict__ w11b, const float* __restrict__ s11, const float* __restrict__ b11,
    const __bf16* __restrict__ w12b, const float* __restrict__ s12, const float* __restrict__ b12,
    __bf16* __restrict__ maxed)
{
  __shared__ __align__(16) __bf16 Xs[64 * 256];   // 32 KB staging / Y1 / Mst
  __shared__ __align__(16) __bf16 Y0[32 * 256];   // 16 KB dedicated L0 output
  __bf16* const Y1 = Xs;                          // lower 16KB (post-bar2)
  __bf16* const Mst = Xs + 32 * 256;              // upper 16KB (post-bar3)

  const int b = blockIdx.y;
  const int n0 = blockIdx.x * 8;
  const int tid = threadIdx.x;
  const int wave = tid >> 6, lane = tid & 63;
  const int lrow = lane & 15, quad = lane >> 4;
  const int c0 = 32 * wave;
  const int idxbase = (b * N_ + n0) * K_;

  // ---- stage DMA: wave w stages rows [16w,16w+16) (2 rows per instr:
  // lanes 0-31 -> row r, lanes 32-63 -> row r+1; 1KB linear dest).
  // Source 16B chunk XORed by (row&7) so swizzled L0 reads are conflict-free.
  {
    const int r0 = wave * 16;
    const int hf = lane >> 5;
    const int ch = lane & 31;
    int mr[8];
    #pragma unroll
    for (int i = 0; i < 8; i++)
      mr[i] = idx[idxbase + r0 + 2 * i + hf];
    #pragma unroll
    for (int i = 0; i < 8; i++) {
      const int r = r0 + 2 * i + hf;
      const char* src = (const char*)f2t
          + (((size_t)(b * M_ + mr[i])) << 9)
          + ((ch << 4) ^ ((r & 7) << 4));
      __builtin_amdgcn_global_load_lds(
          (const AS1G unsigned int*)src,
          (AS3L unsigned int*)(Xs + (r0 + 2 * i) * 256),
          16, 0, 0);
    }
  }

  // ---- posdiff last-k fragment (quad 0 lanes only) while DMA in flight
  bf16x8 xlast[4];
  #pragma unroll
  for (int pt = 0; pt < 4; pt++) { bf16x8 v = {}; xlast[pt] = v; }
  if (quad == 0) {
    #pragma unroll
    for (int pt = 0; pt < 4; pt++) {
      const int r = pt * 16 + lrow;
      const int m = idx[idxbase + r];
      const int n = n0 + (r >> 3);
      bf16x8 v = {};
      v[0] = (__bf16)(pos2[b * 3 * M_ + m]          - pos1[b * 3 * N_ + n]);
      v[1] = (__bf16)(pos2[b * 3 * M_ + M_ + m]     - pos1[b * 3 * N_ + N_ + n]);
      v[2] = (__bf16)(pos2[b * 3 * M_ + 2 * M_ + m] - pos1[b * 3 * N_ + 2 * N_ + n]);
      xlast[pt] = v;
    }
  }

  // W k-step-0 fragments issued before the barrier
  bf16x8 wf0 = *(const bf16x8*)(w0p + (size_t)(c0 + lrow) * 288 + quad * 8);
  bf16x8 wf1 = *(const bf16x8*)(w0p + (size_t)(c0 + 16 + lrow) * 288 + quad * 8);

  __syncthreads();                 // (1) all DMAs complete

  // ---- L0: K=288 = 8 LDS ksteps + posdiff step; epilogue flows straight
  // into dedicated Y0 (no mid-block barrier).
  {
    floatx4 acc[4][2];
    const floatx4 fz = {0.f, 0.f, 0.f, 0.f};
    #pragma unroll
    for (int pt = 0; pt < 4; pt++) { acc[pt][0] = fz; acc[pt][1] = fz; }

    const int swz = (lrow & 7) << 4;
    bf16x8 xf[4];
    #pragma unroll
    for (int pt = 0; pt < 4; pt++)
      xf[pt] = *(const bf16x8*)((const char*)Xs + (pt * 16 + lrow) * 512
                                + ((quad * 16) ^ swz));

    #pragma unroll
    for (int ks = 0; ks < 9; ks++) {
      bf16x8 wn0, wn1, xn[4];
      if (ks < 8) {
        const int kn = (ks + 1) * 32 + quad * 8;
        wn0 = *(const bf16x8*)(w0p + (size_t)(c0 + lrow) * 288 + kn);
        wn1 = *(const bf16x8*)(w0p + (size_t)(c0 + 16 + lrow) * 288 + kn);
        if (ks < 7) {
          const int kb = ((ks + 1) * 64 + quad * 16) ^ swz;
          #pragma unroll
          for (int pt = 0; pt < 4; pt++)
            xn[pt] = *(const bf16x8*)((const char*)Xs + (pt * 16 + lrow) * 512 + kb);
        } else {
          #pragma unroll
          for (int pt = 0; pt < 4; pt++) xn[pt] = xlast[pt];
        }
      }
      #pragma unroll
      for (int pt = 0; pt < 4; pt++) {
        acc[pt][0] = __builtin_amdgcn_mfma_f32_16x16x32_bf16(wf0, xf[pt], acc[pt][0], 0, 0, 0);
        acc[pt][1] = __builtin_amdgcn_mfma_f32_16x16x32_bf16(wf1, xf[pt], acc[pt][1], 0, 0, 0);
      }
      if (ks < 8) {
        wf0 = wn0; wf1 = wn1;
        #pragma unroll
        for (int pt = 0; pt < 4; pt++) xf[pt] = xn[pt];
      }
    }

    // epilogue -> Y0 (dedicated), swizzled 256B rows
    #pragma unroll
    for (int pt = 0; pt < 4; pt++) {
      #pragma unroll
      for (int wt = 0; wt < 2; wt++) {
        const int colg = c0 + wt * 16 + quad * 4;
        floatx4 s4 = *(const floatx4*)(s10 + colg);
        floatx4 b4 = *(const floatx4*)(b10 + colg);
        bf16x4 pk;
        #pragma unroll
        for (int r = 0; r < 4; r++) {
          float v = acc[pt][wt][r] * s4[r] + b4[r];
          pk[r] = (__bf16)(v > 0.f ? v : 0.f);
        }
        const int row = pt * 16 + lrow;
        const int cb = colg * 2;
        *(bf16x4*)((char*)Y0 + row * 256
                   + ((cb & ~15) ^ ((row & 7) << 4)) + (cb & 15)) = pk;
      }
    }
  }
  __syncthreads();                 // (2) Y0 ready; all Xs reads done

  // ---- L1: 128 -> 128, Y0 -> Y1 (aliases Xs lower 16KB)
  {
    floatx4 a1c[4][2];
    mfma_kloop_swz<4>(Y0, w11b, 128, c0, lane, a1c);
    #pragma unroll
    for (int pt = 0; pt < 4; pt++) {
      #pragma unroll
      for (int wt = 0; wt < 2; wt++) {
        const int colg = c0 + wt * 16 + quad * 4;
        floatx4 s4 = *(const floatx4*)(s11 + colg);
        floatx4 b4 = *(const floatx4*)(b11 + colg);
        bf16x4 pk;
        #pragma unroll
        for (int r = 0; r < 4; r++) {
          float v = a1c[pt][wt][r] * s4[r] + b4[r];
          pk[r] = (__bf16)(v > 0.f ? v : 0.f);
        }
        const int row = pt * 16 + lrow;
        const int cb = colg * 2;
        *(bf16x4*)((char*)Y1 + row * 256
                   + ((cb & ~15) ^ ((row & 7) << 4)) + (cb & 15)) = pk;
      }
    }
  }
  __syncthreads();                 // (3) Y1 ready; Mst alias safe

  // ---- L2: two 128-col passes, IN-REGISTER maxpool (shfl_xor 1,2,4),
  // per-wave col-disjoint Mst writes (no barrier between passes).
  #pragma unroll
  for (int p = 0; p < 2; p++) {
    floatx4 a2c[4][2];
    mfma_kloop_swz<4>(Y1, w12b, 128, 128 * p + c0, lane, a2c);
    #pragma unroll
    for (int pt = 0; pt < 4; pt++) {
      #pragma unroll
      for (int wt = 0; wt < 2; wt++) {
        const int colg = 128 * p + c0 + wt * 16 + quad * 4;
        floatx4 s4 = *(const floatx4*)(s12 + colg);
        floatx4 b4 = *(const floatx4*)(b12 + colg);
        floatx4 v;
        #pragma unroll
        for (int r = 0; r < 4; r++) {
          float t = a2c[pt][wt][r] * s4[r] + b4[r];
          v[r] = t > 0.f ? t : 0.f;
        }
        #pragma unroll
        for (int st = 1; st <= 4; st <<= 1) {
          #pragma unroll
          for (int r = 0; r < 4; r++)
            v[r] = fmaxf(v[r], __shfl_xor(v[r], st, 64));
        }
        if ((lrow & 7) == 0) {
          const int point = pt * 2 + (lrow >> 3);
          bf16x4 pk;
          #pragma unroll
          for (int r = 0; r < 4; r++) pk[r] = (__bf16)v[r];
          *(bf16x4*)(Mst + point * 264 + colg) = pk;
        }
      }
    }
  }
  __syncthreads();                 // (4) Mst complete

  // ---- store: full 512B per point row, 32 consecutive lanes (full lines)
  {
    const int point = tid >> 5, ch = tid & 31;
    bf16x8 v = *(const bf16x8*)(Mst + point * 264 + ch * 8);
    *(bf16x8*)(maxed + ((size_t)(b * N_ + n0 + point)) * 256 + ch * 8) = v;
  }
}

// ---------------------------------------------------------------------------
// MLP2 v3 (unchanged from R7/R8): LDS-staged A-panel, 32 rows x 256 out-cols
// per block, grid 1024. One barrier, dense k-loop, 8 MFMA/kstep.
// ---------------------------------------------------------------------------
__global__ __launch_bounds__(256, 3) void mlp2_kernel(
    const __bf16* __restrict__ maxed, const __bf16* __restrict__ f1t,
    const __bf16* __restrict__ w20b, const float* __restrict__ s20,
    const float* __restrict__ b20, float* __restrict__ out)
{
  __shared__ __align__(16) __bf16 As[2][32 * 256];   // 32 KB total
  const int rows0 = blockIdx.x * 32;                 // global row = b*N + n
  const int b = rows0 >> 13;
  const int nbase = rows0 & (N_ - 1);
  const int tid = threadIdx.x;
  const int wave = tid >> 6, lane = tid & 63;
  const int lrow = lane & 15, quad = lane >> 4;
  const int c0 = 64 * wave;                          // wave's 64 out-cols

  {
    const int r0 = wave * 8;
    const int hf = lane >> 5, ch = lane & 31;
    #pragma unroll
    for (int i = 0; i < 4; i++) {
      const int r = r0 + 2 * i + hf;
      const size_t srow = ((size_t)(rows0 + r)) << 9;     // 512B rows
      const int so = (ch << 4) ^ ((r & 7) << 4);
      __builtin_amdgcn_global_load_lds(
          (const AS1G unsigned int*)((const char*)maxed + srow + so),
          (AS3L unsigned int*)(&As[0][(r0 + 2 * i) * 256]), 16, 0, 0);
      __builtin_amdgcn_global_load_lds(
          (const AS1G unsigned int*)((const char*)f1t + srow + so),
          (AS3L unsigned int*)(&As[1][(r0 + 2 * i) * 256]), 16, 0, 0);
    }
  }

  bf16x8 wf[4];
  #pragma unroll
  for (int wt = 0; wt < 4; wt++)
    wf[wt] = *(const bf16x8*)(w20b + (size_t)(c0 + wt * 16 + lrow) * 512 + quad * 8);

  __syncthreads();                 // staging DMAs complete

  floatx4 acc[2][4];
  const floatx4 fz = {0.f, 0.f, 0.f, 0.f};
  #pragma unroll
  for (int mt = 0; mt < 2; mt++)
    #pragma unroll
    for (int wt = 0; wt < 4; wt++) acc[mt][wt] = fz;

  auto aaddr = [&](int ks, int mt) -> const char* {
    const int row = mt * 16 + lrow;
    return (const char*)(&As[ks >> 3][0]) + row * 512
           + ((((ks & 7) * 64) + quad * 16) ^ ((row & 7) << 4));
  };

  bf16x8 af[2];
  af[0] = *(const bf16x8*)aaddr(0, 0);
  af[1] = *(const bf16x8*)aaddr(0, 1);

  #pragma unroll
  for (int ks = 0; ks < 16; ks++) {
    bf16x8 wn[4], an[2];
    if (ks < 15) {
      const int kn = (ks + 1) * 32 + quad * 8;
      #pragma unroll
      for (int wt = 0; wt < 4; wt++)
        wn[wt] = *(const bf16x8*)(w20b + (size_t)(c0 + wt * 16 + lrow) * 512 + kn);
      an[0] = *(const bf16x8*)aaddr(ks + 1, 0);
      an[1] = *(const bf16x8*)aaddr(ks + 1, 1);
    }
    #pragma unroll
    for (int mt = 0; mt < 2; mt++)
      #pragma unroll
      for (int wt = 0; wt < 4; wt++)
        acc[mt][wt] = __builtin_amdgcn_mfma_f32_16x16x32_bf16(af[mt], wf[wt], acc[mt][wt], 0, 0, 0);
    if (ks < 15) {
      #pragma unroll
      for (int wt = 0; wt < 4; wt++) wf[wt] = wn[wt];
      af[0] = an[0]; af[1] = an[1];
    }
  }

  #pragma unroll
  for (int wt = 0; wt < 4; wt++) {
    const int col = c0 + wt * 16 + lrow;
    const float s = s20[col];
    const float bb = b20[col];
    #pragma unroll
    for (int mt = 0; mt < 2; mt++) {
      floatx4 pk;
      #pragma unroll
      for (int r = 0; r < 4; r++) {
        float v = acc[mt][wt][r] * s + bb;
        pk[r] = v > 0.f ? v : 0.f;
      }
      const int n = nbase + mt * 16 + quad * 4;
      *(floatx4*)(out + ((size_t)(b * 256 + col)) * N_ + n) = pk;
    }
  }
}

// ---------------------------------------------------------------------------
extern "C" void kernel_launch(void* const* d_in, const int* in_sizes, int n_in,
                              void* d_out, int out_size, void* d_ws, size_t ws_size,
                              hipStream_t stream)
{
  const float* pos1     = (const float*)d_in[0];
  const float* pos2     = (const float*)d_in[1];
  const float* feature1 = (const float*)d_in[2];
  const float* feature2 = (const float*)d_in[3];
  const float* w1_0 = (const float*)d_in[4];
  const float* s1_0 = (const float*)d_in[5];
  const float* b1_0 = (const float*)d_in[6];
  const float* w1_1 = (const float*)d_in[7];
  const float* s1_1 = (const float*)d_in[8];
  const float* b1_1 = (const float*)d_in[9];
  const float* w1_2 = (const float*)d_in[10];
  const float* s1_2 = (const float*)d_in[11];
  const float* b1_2 = (const float*)d_in[12];
  const float* w2_0 = (const float*)d_in[13];
  const float* s2_0 = (const float*)d_in[14];
  const float* b2_0 = (const float*)d_in[15];

  // Workspace layout (39,231,488 B total)
  char* ws = (char*)d_ws;
  int*    idx   = (int*)(ws);                    //  1,048,576 @ 0
  __bf16* f2t   = (__bf16*)(ws + 1048576);       //  4,194,304
  __bf16* f1t   = (__bf16*)(ws + 5242880);       // 16,777,216
  __bf16* maxed = (__bf16*)(ws + 22020096);      // 16,777,216
  __bf16* w0p   = (__bf16*)(ws + 38797312);      //     73,728
  __bf16* w11b  = (__bf16*)(ws + 38871040);      //     32,768
  __bf16* w12b  = (__bf16*)(ws + 38903808);      //     65,536
  __bf16* w20b  = (__bf16*)(ws + 38969344);      //    262,144
  // part (8 MB, 4 lists) aliases maxed: written by pre_knn, read by
  // knn_merge, clobbered only later by mlp1 (stream-ordered).
  u64k*   part  = (u64k*)(ws + 22020096);

  pre_knn<<<dim3(13136), 256, 0, stream>>>(
      w1_0, w1_1, w1_2, w2_0, feature1, feature2, pos1, pos2,
      w0p, w11b, w12b, w20b, f2t, f1t, part);
  knn_merge<<<dim3(N_ * B_ / 256), 256, 0, stream>>>(part, idx);
  mlp1_kernel<<<dim3(N_ / 8, B_), 256, 0, stream>>>(
      pos1, pos2, idx, f2t, w0p, s1_0, b1_0, w11b, s1_1, b1_1, w12b, s1_2, b1_2, maxed);
  mlp2_kernel<<<dim3(N_ * B_ / 32), 256, 0, stream>>>(maxed, f1t, w20b, s2_0, b2_0,
                                                      (float*)d_out);
}

// Round 10
// 299.512 us; speedup vs baseline: 1.0399x; 1.0399x over previous
//
#include <hip/hip_runtime.h>
#include <hip/hip_bf16.h>

#define B_ 4
#define N_ 8192
#define M_ 2048
#define K_ 8

typedef __bf16 bf16x8 __attribute__((ext_vector_type(8)));
typedef __bf16 bf16x4 __attribute__((ext_vector_type(4)));
typedef float  floatx4 __attribute__((ext_vector_type(4)));
typedef unsigned long long u64k;

#define AS1G __attribute__((address_space(1)))
#define AS3L __attribute__((address_space(3)))

// ---------------------------------------------------------------------------
// PRE_KNN (fused independent work) -- byte-identical to R8:
//   blocks [0,2048)      : KNN split-4, 64 pts & 512 candidates per block
//   blocks [2048,4096)   : feature2 fp32 -> f2t bf16 transpose
//   blocks [4096,12288)  : feature1 fp32 -> f1t bf16 transpose
//   blocks [12288,13136) : weight casts (w1_0 padded 259->288)
// smem = 24576 B -> 6 blocks/CU for the VALU-bound scan.
// ---------------------------------------------------------------------------
__device__ __forceinline__ void ce(u64k& a, u64k& b) {
  u64k lo = a < b ? a : b;
  u64k hi = a < b ? b : a;
  a = lo; b = hi;
}

// low-8 of merge(a asc, c asc), result sorted ascending (bitonic clean)
__device__ __forceinline__ void merge8(u64k (&a)[8], const u64k (&c)[8]) {
  #pragma unroll
  for (int k = 0; k < 8; k++) { u64k x = c[7 - k]; a[k] = a[k] < x ? a[k] : x; }
  ce(a[0], a[4]); ce(a[1], a[5]); ce(a[2], a[6]); ce(a[3], a[7]);
  ce(a[0], a[2]); ce(a[1], a[3]); ce(a[4], a[6]); ce(a[5], a[7]);
  ce(a[0], a[1]); ce(a[2], a[3]); ce(a[4], a[5]); ce(a[6], a[7]);
}

__global__ __launch_bounds__(256) void pre_knn(
    const float* __restrict__ w10, const float* __restrict__ w11,
    const float* __restrict__ w12, const float* __restrict__ w20,
    const float* __restrict__ feature1, const float* __restrict__ feature2,
    const float* __restrict__ pos1, const float* __restrict__ pos2,
    __bf16* __restrict__ w0p, __bf16* __restrict__ w11b,
    __bf16* __restrict__ w12b, __bf16* __restrict__ w20b,
    __bf16* __restrict__ f2t, __bf16* __restrict__ f1t,
    u64k* __restrict__ part)
{
  __shared__ __align__(16) char smem[24576];
  const int bid = blockIdx.x;
  const int tid = threadIdx.x;

  if (bid < 2048) {
    // ---------------- KNN (split-4) ----------------
    floatx4* P = (floatx4*)smem;                     // 512 x 16B = 8 KB
    u64k (*md)[32] = (u64k(*)[32])(smem + 8192);     // 16 KB (unpadded)
    const int b = (bid >> 7) & 3;
    const int quarter = bid >> 9;                    // 0..3
    const int n0 = (bid & 127) * 64;
    const int cbase = quarter * 512;

    const float* p2 = pos2 + b * 3 * M_;
    for (int i = tid; i < 512; i += 256) {
      const int c = cbase + i;
      float x = p2[c], y = p2[M_ + c], z = p2[2 * M_ + c];
      floatx4 q;
      q[0] = x; q[1] = y; q[2] = z;
      q[3] = __fadd_rn(__fadd_rn(__fmul_rn(x, x), __fmul_rn(y, y)), __fmul_rn(z, z));
      P[i] = q;
    }
    __syncthreads();

    const int p = tid >> 2, t = tid & 3;
    const int n = n0 + p;
    const float* p1 = pos1 + b * 3 * N_;
    const float x1 = p1[n], y1 = p1[N_ + n], z1 = p1[2 * N_ + n];
    const float r1 = __fadd_rn(__fadd_rn(__fmul_rn(x1, x1), __fmul_rn(y1, y1)),
                               __fmul_rn(z1, z1));

    u64k bd[8];
    #pragma unroll
    for (int r = 0; r < 8; r++) bd[r] = ~0ULL;   // sentinel > any real key

    for (int bb = 0; bb < 16; ++bb) {
      // interleaved per-thread stream (index-ascending): local c = 4*(8bb+i)+t
      floatx4 q[8];
      #pragma unroll
      for (int i = 0; i < 8; i++) q[i] = P[4 * (8 * bb + i) + t];

      u64k s[8];
      #pragma unroll
      for (int i = 0; i < 8; i++) {
        float dot = __fadd_rn(__fadd_rn(__fmul_rn(x1, q[i][0]), __fmul_rn(y1, q[i][1])),
                              __fmul_rn(z1, q[i][2]));
        float d = __fsub_rn(__fadd_rn(r1, q[i][3]), __fmul_rn(2.0f, dot));
        unsigned du = __float_as_uint(d);
        unsigned k32 = du ^ ((unsigned)((int)du >> 31) | 0x80000000u);  // monotone
        s[i] = ((u64k)k32 << 11) | (unsigned)(cbase + 4 * (8 * bb + i) + t);
      }

      // Batcher odd-even mergesort, 8 elements, 19 comparators
      ce(s[0], s[1]); ce(s[2], s[3]); ce(s[4], s[5]); ce(s[6], s[7]);
      ce(s[0], s[2]); ce(s[1], s[3]); ce(s[4], s[6]); ce(s[5], s[7]);
      ce(s[1], s[2]); ce(s[5], s[6]);
      ce(s[0], s[4]); ce(s[1], s[5]); ce(s[2], s[6]); ce(s[3], s[7]);
      ce(s[2], s[4]); ce(s[3], s[5]);
      ce(s[1], s[2]); ce(s[3], s[4]); ce(s[5], s[6]);

      if (s[0] < bd[7]) merge8(bd, s);
    }

    // column XOR-swizzle (t-field) replaces +1 row pad for bank spread
    {
      const int swp = (p & 3) << 3;
      #pragma unroll
      for (int r = 0; r < 8; r++) md[p][(t * 8 + r) ^ swp] = bd[r];
    }
    __syncthreads();

    // 4-way lexicographic merge of the sorted lists == lax.top_k order
    if (tid < 64) {
      const int sw = tid & 3;
      const int b0 = (0 ^ sw) << 3, b1 = (1 ^ sw) << 3;
      const int b2 = (2 ^ sw) << 3, b3 = (3 ^ sw) << 3;
      int h0 = 0, h1 = 0, h2 = 0, h3 = 0;
      u64k* o = part + ((size_t)((b * 4 + quarter) * N_ + n0 + tid)) * 8;
      #pragma unroll
      for (int r = 0; r < 8; r++) {
        u64k k0 = md[tid][b0 + h0], k1 = md[tid][b1 + h1];
        u64k k2 = md[tid][b2 + h2], k3 = md[tid][b3 + h3];
        u64k m01 = k0 < k1 ? k0 : k1;
        u64k m23 = k2 < k3 ? k2 : k3;
        u64k m = m01 < m23 ? m01 : m23;
        h0 += (k0 == m); h1 += (k1 == m); h2 += (k2 == m); h3 += (k3 == m);
        o[r] = m;
      }
    }
  } else if (bid < 4096) {
    // ---------------- feature2 transpose+cast (L = M_) ----------------
    float (*tile)[33] = (float(*)[33])smem;
    const int tb = bid - 2048;
    const int C = 256, L = M_;
    const int b = tb >> 9;
    const int c0 = ((tb >> 6) & 7) * 32, l0 = (tb & 63) * 32;
    const int tx = tid & 31, ty = tid >> 5;
    const float* src = feature2 + (size_t)b * C * L;
    #pragma unroll
    for (int i = 0; i < 4; i++)
      tile[ty + 8 * i][tx] = src[(size_t)(c0 + ty + 8 * i) * L + l0 + tx];
    __syncthreads();
    __bf16* dst = f2t + (size_t)b * L * C;
    #pragma unroll
    for (int i = 0; i < 4; i++)
      dst[(size_t)(l0 + ty + 8 * i) * C + c0 + tx] = (__bf16)tile[tx][ty + 8 * i];
  } else if (bid < 12288) {
    // ---------------- feature1 transpose+cast (L = N_) ----------------
    float (*tile)[33] = (float(*)[33])smem;
    const int tb = bid - 4096;
    const int C = 256, L = N_;
    const int b = tb >> 11;
    const int c0 = ((tb >> 8) & 7) * 32, l0 = (tb & 255) * 32;
    const int tx = tid & 31, ty = tid >> 5;
    const float* src = feature1 + (size_t)b * C * L;
    #pragma unroll
    for (int i = 0; i < 4; i++)
      tile[ty + 8 * i][tx] = src[(size_t)(c0 + ty + 8 * i) * L + l0 + tx];
    __syncthreads();
    __bf16* dst = f1t + (size_t)b * L * C;
    #pragma unroll
    for (int i = 0; i < 4; i++)
      dst[(size_t)(l0 + ty + 8 * i) * C + c0 + tx] = (__bf16)tile[tx][ty + 8 * i];
  } else {
    // ---------------- weight casts ----------------
    int t = (bid - 12288) * 256 + tid;
    if (t < 36864) {
      int o = t / 288, c = t - o * 288;
      w0p[t] = (c < 259) ? (__bf16)w10[o * 259 + c] : (__bf16)0.0f;
    } else if (t < 53248) {
      int i = t - 36864; w11b[i] = (__bf16)w11[i];
    } else if (t < 86016) {
      int i = t - 53248; w12b[i] = (__bf16)w12[i];
    } else if (t < 217088) {
      int i = t - 86016; w20b[i] = (__bf16)w20[i];
    }
  }
}

// ---------------------------------------------------------------------------
// Merge the four candidate-quarter sorted-8 key lists -> final neighbor
// indices (byte-identical to R8).
// ---------------------------------------------------------------------------
__global__ __launch_bounds__(256) void knn_merge(
    const u64k* __restrict__ part, int* __restrict__ idx_out)
{
  const int pt = blockIdx.x * 256 + threadIdx.x;     // 0..32767
  const int b = pt >> 13, n = pt & (N_ - 1);
  u64k a01[8], c1[8], a23[8], c3[8];
  {
    const u64k* l0 = part + ((size_t)((b * 4 + 0) * N_ + n)) * 8;
    const u64k* l1 = part + ((size_t)((b * 4 + 1) * N_ + n)) * 8;
    const u64k* l2 = part + ((size_t)((b * 4 + 2) * N_ + n)) * 8;
    const u64k* l3 = part + ((size_t)((b * 4 + 3) * N_ + n)) * 8;
    #pragma unroll
    for (int r = 0; r < 8; r++) {
      a01[r] = l0[r]; c1[r] = l1[r]; a23[r] = l2[r]; c3[r] = l3[r];
    }
  }
  merge8(a01, c1);
  merge8(a23, c3);
  merge8(a01, a23);
  int* o = idx_out + (size_t)pt * 8;
  #pragma unroll
  for (int r = 0; r < 8; r++) o[r] = (int)(a01[r] & 2047u);
}

// ---------------------------------------------------------------------------
// LDS-input MFMA layer (v2-exact, 136-stride Y tiles): X from LDS, weights
// global with next-kstep register prefetch. PT=4 x WT=2. The 136-elem (272B)
// row stride gives a free 2-way bank aliasing on ds_read_b128.
// Fragment maps (gfx950, HW-verified): A[m=lane&15][k=quad*8+j],
// B[n=lane&15][k=quad*8+j], D[row=quad*4+reg][col=lane&15].
// ---------------------------------------------------------------------------
template <int KSTEPS>
__device__ __forceinline__ void mfma_layer_lds(
    const __bf16* X, const __bf16* W, int wstride,
    const float* sv, const float* bv,
    __bf16* Y, int ycolbase, int c0, int lane)
{
  const int lrow = lane & 15, quad = lane >> 4;
  floatx4 acc[4][2];
  const floatx4 fz = {0.f, 0.f, 0.f, 0.f};
  #pragma unroll
  for (int pt = 0; pt < 4; pt++) { acc[pt][0] = fz; acc[pt][1] = fz; }

  bf16x8 wf0 = *(const bf16x8*)(W + (size_t)(c0 + lrow) * wstride + quad * 8);
  bf16x8 wf1 = *(const bf16x8*)(W + (size_t)(c0 + 16 + lrow) * wstride + quad * 8);
  bf16x8 xf[4];
  #pragma unroll
  for (int pt = 0; pt < 4; pt++)
    xf[pt] = *(const bf16x8*)(X + (pt * 16 + lrow) * 136 + quad * 8);

  #pragma unroll
  for (int ks = 0; ks < KSTEPS; ks++) {
    bf16x8 wn0, wn1, xn[4];
    if (ks + 1 < KSTEPS) {
      const int kn = (ks + 1) * 32 + quad * 8;
      wn0 = *(const bf16x8*)(W + (size_t)(c0 + lrow) * wstride + kn);
      wn1 = *(const bf16x8*)(W + (size_t)(c0 + 16 + lrow) * wstride + kn);
      #pragma unroll
      for (int pt = 0; pt < 4; pt++)
        xn[pt] = *(const bf16x8*)(X + (pt * 16 + lrow) * 136 + kn);
    }
    #pragma unroll
    for (int pt = 0; pt < 4; pt++) {
      acc[pt][0] = __builtin_amdgcn_mfma_f32_16x16x32_bf16(wf0, xf[pt], acc[pt][0], 0, 0, 0);
      acc[pt][1] = __builtin_amdgcn_mfma_f32_16x16x32_bf16(wf1, xf[pt], acc[pt][1], 0, 0, 0);
    }
    if (ks + 1 < KSTEPS) {
      wf0 = wn0; wf1 = wn1;
      #pragma unroll
      for (int pt = 0; pt < 4; pt++) xf[pt] = xn[pt];
    }
  }

  #pragma unroll
  for (int pt = 0; pt < 4; pt++) {
    #pragma unroll
    for (int wt = 0; wt < 2; wt++) {
      const int colg = c0 + wt * 16 + quad * 4;    // 4 consecutive out cols
      floatx4 s4 = *(const floatx4*)(sv + colg);
      floatx4 b4 = *(const floatx4*)(bv + colg);
      bf16x4 pk;
      #pragma unroll
      for (int r = 0; r < 4; r++) {
        float v = acc[pt][wt][r] * s4[r] + b4[r];
        pk[r] = (__bf16)(v > 0.f ? v : 0.f);
      }
      *(bf16x4*)(Y + (pt * 16 + lrow) * 136 + (colg - ycolbase)) = pk;
    }
  }
}

// ---------------------------------------------------------------------------
// MLP1 -- byte-level revert to the R2 kernel ("v2"), the fastest measured
// configuration (99.6us; every later restructure regressed: v4 110, v5 105,
// v5@(256,3) 113, v7 126). Staged gathers via global_load_lds + source-XOR
// swizzle; dedicated Y0[64*136]; Y1 aliases Xs; LDS-read maxpool by 128
// threads (NOT shfl -- ds_bpermute maxpool was +5us of LDS-pipe traffic).
// LDS = 51.7KB -> 3 blocks/CU; (256,3) -> 76 VGPR keeps the prefetch
// pipeline in registers.
// ---------------------------------------------------------------------------
__global__ __launch_bounds__(256, 3) void mlp1_kernel(
    const float* __restrict__ pos1, const float* __restrict__ pos2,
    const int* __restrict__ idx, const __bf16* __restrict__ f2t,
    const __bf16* __restrict__ w0p, const float* __restrict__ s10, const float* __restrict__ b10,
    const __bf16* __restrict__ w11b, const float* __restrict__ s11, const float* __restrict__ b11,
    const __bf16* __restrict__ w12b, const float* __restrict__ s12, const float* __restrict__ b12,
    __bf16* __restrict__ maxed)
{
  __shared__ __align__(16) __bf16 Xs[64 * 256];   // 32 KB staged gathers (swizzled); Y1 aliases
  __shared__ __align__(16) __bf16 Y0[64 * 136];   // 17.4 KB
  __shared__ int mrow[64];
  __shared__ __align__(16) float dp[64][4];
  __bf16* const Y1 = Xs;                          // X dead after L0

  const int b = blockIdx.y;
  const int n0 = blockIdx.x * 8;
  const int tid = threadIdx.x;
  const int wave = tid >> 6, lane = tid & 63;
  const int lrow = lane & 15, quad = lane >> 4;
  const int c0 = 32 * wave;

  // prologue: neighbor index + posdiff per row (row r = point g, rank k)
  if (tid < 64) {
    const int r = tid, g = r >> 3;
    const int m = idx[(b * N_ + n0) * K_ + r];
    mrow[r] = m;
    const int n = n0 + g;
    dp[r][0] = pos2[b * 3 * M_ + m]          - pos1[b * 3 * N_ + n];
    dp[r][1] = pos2[b * 3 * M_ + M_ + m]     - pos1[b * 3 * N_ + N_ + n];
    dp[r][2] = pos2[b * 3 * M_ + 2 * M_ + m] - pos1[b * 3 * N_ + 2 * N_ + n];
    dp[r][3] = 0.f;
  }
  __syncthreads();

  // ---- stage: wave w DMAs rows [16w,16w+16) of the gather into Xs.
  // Per instr: lanes 0-31 = row r, lanes 32-63 = row r+1 (1 KB linear dest).
  // Source chunk index XORed by (row&7) so swizzled reads are conflict-free.
  {
    const int r0 = wave * 16;
    const int half = lane >> 5;          // which row of the pair
    const int ch = lane & 31;            // 16B chunk within the 512B row
    #pragma unroll
    for (int i = 0; i < 8; i++) {
      const int r = r0 + 2 * i + half;
      const int m = mrow[r];
      const char* src = (const char*)f2t
          + (((size_t)(b * M_ + m)) << 9)
          + ((ch << 4) ^ ((r & 7) << 4));
      __builtin_amdgcn_global_load_lds(
          (const AS1G unsigned int*)src,
          (AS3L unsigned int*)(Xs + (r0 + 2 * i) * 256),
          16, 0, 0);
    }
  }

  // last k-step fragment (posdiff) built in registers while DMA in flight
  bf16x8 xlast[4];
  #pragma unroll
  for (int pt = 0; pt < 4; pt++) {
    bf16x8 v = {};
    if (quad == 0) {               // k=256..263: [dx,dy,dz,0,...]
      floatx4 d = *(const floatx4*)(&dp[pt * 16 + lrow][0]);
      v[0] = (__bf16)d[0]; v[1] = (__bf16)d[1]; v[2] = (__bf16)d[2];
    }
    xlast[pt] = v;                 // quads 1-3 zero (w0p zero-padded too)
  }

  // W k-step-0 fragments issued before the barrier (L1/L2-resident)
  bf16x8 wf0 = *(const bf16x8*)(w0p + (size_t)(c0 + lrow) * 288 + quad * 8);
  bf16x8 wf1 = *(const bf16x8*)(w0p + (size_t)(c0 + 16 + lrow) * 288 + quad * 8);

  __syncthreads();                 // drains the global_load_lds DMA

  // ---- L0: K=288 = 8 LDS ksteps + posdiff step. Out -> Y0.
  {
    floatx4 acc[4][2];
    const floatx4 fz = {0.f, 0.f, 0.f, 0.f};
    #pragma unroll
    for (int pt = 0; pt < 4; pt++) { acc[pt][0] = fz; acc[pt][1] = fz; }

    const int swz = (lrow & 7) << 4;     // byte XOR within a 512B row
    bf16x8 xf[4];
    #pragma unroll
    for (int pt = 0; pt < 4; pt++)
      xf[pt] = *(const bf16x8*)((const char*)Xs + (pt * 16 + lrow) * 512
                                + ((quad * 16) ^ swz));

    #pragma unroll
    for (int ks = 0; ks < 9; ks++) {
      bf16x8 wn0, wn1, xn[4];
      if (ks < 8) {
        const int kn = (ks + 1) * 32 + quad * 8;
        wn0 = *(const bf16x8*)(w0p + (size_t)(c0 + lrow) * 288 + kn);
        wn1 = *(const bf16x8*)(w0p + (size_t)(c0 + 16 + lrow) * 288 + kn);
        if (ks < 7) {
          const int kb = ((ks + 1) * 64 + quad * 16) ^ swz;
          #pragma unroll
          for (int pt = 0; pt < 4; pt++)
            xn[pt] = *(const bf16x8*)((const char*)Xs + (pt * 16 + lrow) * 512 + kb);
        } else {
          #pragma unroll
          for (int pt = 0; pt < 4; pt++) xn[pt] = xlast[pt];
        }
      }
      #pragma unroll
      for (int pt = 0; pt < 4; pt++) {
        acc[pt][0] = __builtin_amdgcn_mfma_f32_16x16x32_bf16(wf0, xf[pt], acc[pt][0], 0, 0, 0);
        acc[pt][1] = __builtin_amdgcn_mfma_f32_16x16x32_bf16(wf1, xf[pt], acc[pt][1], 0, 0, 0);
      }
      if (ks < 8) {
        wf0 = wn0; wf1 = wn1;
        #pragma unroll
        for (int pt = 0; pt < 4; pt++) xf[pt] = xn[pt];
      }
    }
    #pragma unroll
    for (int pt = 0; pt < 4; pt++) {
      #pragma unroll
      for (int wt = 0; wt < 2; wt++) {
        const int colg = c0 + wt * 16 + quad * 4;
        floatx4 s4 = *(const floatx4*)(s10 + colg);
        floatx4 b4 = *(const floatx4*)(b10 + colg);
        bf16x4 pk;
        #pragma unroll
        for (int r = 0; r < 4; r++) {
          float v = acc[pt][wt][r] * s4[r] + b4[r];
          pk[r] = (__bf16)(v > 0.f ? v : 0.f);
        }
        *(bf16x4*)(Y0 + (pt * 16 + lrow) * 136 + colg) = pk;
      }
    }
  }
  __syncthreads();

  // ---- L1: 128 -> 128, Y0 -> Y1 (aliases the now-dead X stage)
  mfma_layer_lds<4>(Y0, w11b, 128, s11, b11, Y1, 0, c0, lane);
  __syncthreads();

  // ---- L2: 128 -> 256 in two 128-col passes (out aliases Y0), maxpool K=8
  #pragma unroll
  for (int p = 0; p < 2; p++) {
    mfma_layer_lds<4>(Y1, w12b, 128, s12, b12, Y0, 128 * p, 128 * p + c0, lane);
    __syncthreads();
    // vectorized maxpool: 128 threads x 8 cols, b128 LDS reads + 16B store
    if (tid < 128) {
      const int g = tid >> 4, cb = (tid & 15) * 8;
      bf16x8 v0 = *(const bf16x8*)(Y0 + (g * 8) * 136 + cb);
      float fmx[8];
      #pragma unroll
      for (int j = 0; j < 8; j++) fmx[j] = (float)v0[j];
      #pragma unroll
      for (int k = 1; k < 8; k++) {
        bf16x8 v = *(const bf16x8*)(Y0 + (g * 8 + k) * 136 + cb);
        #pragma unroll
        for (int j = 0; j < 8; j++) {
          float f = (float)v[j];
          fmx[j] = f > fmx[j] ? f : fmx[j];
        }
      }
      bf16x8 o;
      #pragma unroll
      for (int j = 0; j < 8; j++) o[j] = (__bf16)fmx[j];
      *(bf16x8*)(maxed + ((size_t)(b * N_ + n0 + g)) * 256 + 128 * p + cb) = o;
    }
    __syncthreads();
  }
}

// ---------------------------------------------------------------------------
// MLP2 v3 (byte-identical to R7/R8): LDS-staged A-panel, 32 rows x 256
// out-cols per block, grid 1024. One barrier, dense k-loop, 8 MFMA/kstep.
// ---------------------------------------------------------------------------
__global__ __launch_bounds__(256, 3) void mlp2_kernel(
    const __bf16* __restrict__ maxed, const __bf16* __restrict__ f1t,
    const __bf16* __restrict__ w20b, const float* __restrict__ s20,
    const float* __restrict__ b20, float* __restrict__ out)
{
  __shared__ __align__(16) __bf16 As[2][32 * 256];   // 32 KB total
  const int rows0 = blockIdx.x * 32;                 // global row = b*N + n
  const int b = rows0 >> 13;
  const int nbase = rows0 & (N_ - 1);
  const int tid = threadIdx.x;
  const int wave = tid >> 6, lane = tid & 63;
  const int lrow = lane & 15, quad = lane >> 4;
  const int c0 = 64 * wave;                          // wave's 64 out-cols

  {
    const int r0 = wave * 8;
    const int hf = lane >> 5, ch = lane & 31;
    #pragma unroll
    for (int i = 0; i < 4; i++) {
      const int r = r0 + 2 * i + hf;
      const size_t srow = ((size_t)(rows0 + r)) << 9;     // 512B rows
      const int so = (ch << 4) ^ ((r & 7) << 4);
      __builtin_amdgcn_global_load_lds(
          (const AS1G unsigned int*)((const char*)maxed + srow + so),
          (AS3L unsigned int*)(&As[0][(r0 + 2 * i) * 256]), 16, 0, 0);
      __builtin_amdgcn_global_load_lds(
          (const AS1G unsigned int*)((const char*)f1t + srow + so),
          (AS3L unsigned int*)(&As[1][(r0 + 2 * i) * 256]), 16, 0, 0);
    }
  }

  bf16x8 wf[4];
  #pragma unroll
  for (int wt = 0; wt < 4; wt++)
    wf[wt] = *(const bf16x8*)(w20b + (size_t)(c0 + wt * 16 + lrow) * 512 + quad * 8);

  __syncthreads();                 // staging DMAs complete

  floatx4 acc[2][4];
  const floatx4 fz = {0.f, 0.f, 0.f, 0.f};
  #pragma unroll
  for (int mt = 0; mt < 2; mt++)
    #pragma unroll
    for (int wt = 0; wt < 4; wt++) acc[mt][wt] = fz;

  auto aaddr = [&](int ks, int mt) -> const char* {
    const int row = mt * 16 + lrow;
    return (const char*)(&As[ks >> 3][0]) + row * 512
           + ((((ks & 7) * 64) + quad * 16) ^ ((row & 7) << 4));
  };

  bf16x8 af[2];
  af[0] = *(const bf16x8*)aaddr(0, 0);
  af[1] = *(const bf16x8*)aaddr(0, 1);

  #pragma unroll
  for (int ks = 0; ks < 16; ks++) {
    bf16x8 wn[4], an[2];
    if (ks < 15) {
      const int kn = (ks + 1) * 32 + quad * 8;
      #pragma unroll
      for (int wt = 0; wt < 4; wt++)
        wn[wt] = *(const bf16x8*)(w20b + (size_t)(c0 + wt * 16 + lrow) * 512 + kn);
      an[0] = *(const bf16x8*)aaddr(ks + 1, 0);
      an[1] = *(const bf16x8*)aaddr(ks + 1, 1);
    }
    #pragma unroll
    for (int mt = 0; mt < 2; mt++)
      #pragma unroll
      for (int wt = 0; wt < 4; wt++)
        acc[mt][wt] = __builtin_amdgcn_mfma_f32_16x16x32_bf16(af[mt], wf[wt], acc[mt][wt], 0, 0, 0);
    if (ks < 15) {
      #pragma unroll
      for (int wt = 0; wt < 4; wt++) wf[wt] = wn[wt];
      af[0] = an[0]; af[1] = an[1];
    }
  }

  #pragma unroll
  for (int wt = 0; wt < 4; wt++) {
    const int col = c0 + wt * 16 + lrow;
    const float s = s20[col];
    const float bb = b20[col];
    #pragma unroll
    for (int mt = 0; mt < 2; mt++) {
      floatx4 pk;
      #pragma unroll
      for (int r = 0; r < 4; r++) {
        float v = acc[mt][wt][r] * s + bb;
        pk[r] = v > 0.f ? v : 0.f;
      }
      const int n = nbase + mt * 16 + quad * 4;
      *(floatx4*)(out + ((size_t)(b * 256 + col)) * N_ + n) = pk;
    }
  }
}

// ---------------------------------------------------------------------------
extern "C" void kernel_launch(void* const* d_in, const int* in_sizes, int n_in,
                              void* d_out, int out_size, void* d_ws, size_t ws_size,
                              hipStream_t stream)
{
  const float* pos1     = (const float*)d_in[0];
  const float* pos2     = (const float*)d_in[1];
  const float* feature1 = (const float*)d_in[2];
  const float* feature2 = (const float*)d_in[3];
  const float* w1_0 = (const float*)d_in[4];
  const float* s1_0 = (const float*)d_in[5];
  const float* b1_0 = (const float*)d_in[6];
  const float* w1_1 = (const float*)d_in[7];
  const float* s1_1 = (const float*)d_in[8];
  const float* b1_1 = (const float*)d_in[9];
  const float* w1_2 = (const float*)d_in[10];
  const float* s1_2 = (const float*)d_in[11];
  const float* b1_2 = (const float*)d_in[12];
  const float* w2_0 = (const float*)d_in[13];
  const float* s2_0 = (const float*)d_in[14];
  const float* b2_0 = (const float*)d_in[15];

  // Workspace layout (39,231,488 B total)
  char* ws = (char*)d_ws;
  int*    idx   = (int*)(ws);                    //  1,048,576 @ 0
  __bf16* f2t   = (__bf16*)(ws + 1048576);       //  4,194,304
  __bf16* f1t   = (__bf16*)(ws + 5242880);       // 16,777,216
  __bf16* maxed = (__bf16*)(ws + 22020096);      // 16,777,216
  __bf16* w0p   = (__bf16*)(ws + 38797312);      //     73,728
  __bf16* w11b  = (__bf16*)(ws + 38871040);      //     32,768
  __bf16* w12b  = (__bf16*)(ws + 38903808);      //     65,536
  __bf16* w20b  = (__bf16*)(ws + 38969344);      //    262,144
  // part (8 MB, 4 lists) aliases maxed: written by pre_knn, read by
  // knn_merge, clobbered only later by mlp1 (stream-ordered).
  u64k*   part  = (u64k*)(ws + 22020096);

  pre_knn<<<dim3(13136), 256, 0, stream>>>(
      w1_0, w1_1, w1_2, w2_0, feature1, feature2, pos1, pos2,
      w0p, w11b, w12b, w20b, f2t, f1t, part);
  knn_merge<<<dim3(N_ * B_ / 256), 256, 0, stream>>>(part, idx);
  mlp1_kernel<<<dim3(N_ / 8, B_), 256, 0, stream>>>(
      pos1, pos2, idx, f2t, w0p, s1_0, b1_0, w11b, s1_1, b1_1, w12b, s1_2, b1_2, maxed);
  mlp2_kernel<<<dim3(N_ * B_ / 32), 256, 0, stream>>>(maxed, f1t, w20b, s2_0, b2_0,
                                                      (float*)d_out);
}